// Round 4
// baseline (370.496 us; speedup 1.0000x reference)
//
#include <hip/hip_runtime.h>

#define NEG_INF (-1.0e30f)
#define CAP 4096          // candidate buffer capacity (expected ~100 for this data)
#define NBKT 4096         // 12-bit histogram buckets

__device__ __forceinline__ unsigned flip(float f) {
    // order-preserving map: larger float -> larger uint
    unsigned u = __float_as_uint(f);
    return (u & 0x80000000u) ? ~u : (u | 0x80000000u);
}

__device__ __forceinline__ bool pair_gt(float sa, int ia, float sb, int ib) {
    // descending score, ascending index on ties (matches jax.lax.top_k)
    return (sa > sb) || (sa == sb && ia < ib);
}

// ------- Pass 1: thread-per-row GEMV + fused LDS histogram ----------------------
// Each thread owns whole rows: 16 independent dwordx4 loads in flight, u in VGPRs,
// no cross-lane reduction, coalesced 4B stores. Persistent grid-stride blocks.
__global__ __launch_bounds__(256) void k_gemv_hist(const float* __restrict__ emb,
                                                   const int* __restrict__ p_idx,
                                                   int n_items,
                                                   float* __restrict__ scores,
                                                   unsigned* __restrict__ hist) {
    __shared__ unsigned h[NBKT];
    const int tid = threadIdx.x;
    for (int i = tid; i < NBKT; i += 256) h[i] = 0;

    const float4* uq = (const float4*)(emb + (size_t)(*p_idx) * 64);
    float4 u[16];
#pragma unroll
    for (int c = 0; c < 16; ++c) u[c] = uq[c];   // 64 VGPRs, loop-invariant
    __syncthreads();

    const int stride = gridDim.x * 256;
    for (int row = blockIdx.x * 256 + tid; row < n_items; row += stride) {
        const float4* rp = (const float4*)(emb + (size_t)row * 64);
        float acc = 0.0f;
#pragma unroll
        for (int c = 0; c < 16; ++c) {
            const float4 r = rp[c];              // 16 independent loads in flight
            acc += r.x * u[c].x + r.y * u[c].y + r.z * u[c].z + r.w * u[c].w;
        }
        scores[row] = acc;                       // lanes write consecutive 4B
        atomicAdd(&h[flip(acc) >> 20], 1u);
    }

    __syncthreads();
    for (int i = tid; i < NBKT; i += 256) {
        const unsigned c = h[i];
        if (c) atomicAdd(&hist[i], c);           // sparse merge: ~hundreds per block
    }
}

// ------- Pass 2: compact with inlined boundary-bucket selection -----------------
// Every block redundantly computes B (deterministic), then appends items with
// bucket >= B via global atomic.
__global__ __launch_bounds__(256) void k_compact(const float* __restrict__ scores,
                                                 int n4,
                                                 const unsigned* __restrict__ hist,
                                                 int k,
                                                 unsigned* __restrict__ cnt,
                                                 float* __restrict__ cand_s,
                                                 int* __restrict__ cand_i) {
    __shared__ unsigned h[NBKT];
    __shared__ unsigned psum[256];
    __shared__ unsigned sB;
    const int tid = threadIdx.x;
    for (int i = tid; i < NBKT; i += 256) h[i] = hist[i];
    __syncthreads();
    const int base = tid * 16;
    unsigned local = 0;
#pragma unroll
    for (int j = 0; j < 16; ++j) local += h[base + j];
    psum[tid] = local;
    __syncthreads();
    for (int stride = 1; stride < 256; stride <<= 1) {
        unsigned add = (tid + stride < 256) ? psum[tid + stride] : 0u;
        __syncthreads();
        psum[tid] += add;
        __syncthreads();
    }
    unsigned c = (tid + 1 < 256) ? psum[tid + 1] : 0u;  // items in buckets >= (tid+1)*16
    for (int j = 15; j >= 0; --j) {
        unsigned hb = h[base + j];
        if (c < (unsigned)k && c + hb >= (unsigned)k) sB = (unsigned)(base + j);
        c += hb;
    }
    __syncthreads();
    const unsigned B = sB;

    const float4* s4 = (const float4*)scores;
    for (int i = blockIdx.x * 256 + tid; i < n4; i += gridDim.x * 256) {
        float4 v = s4[i];
        const float vv[4] = {v.x, v.y, v.z, v.w};
#pragma unroll
        for (int j = 0; j < 4; ++j) {
            if ((flip(vv[j]) >> 20) >= B) {
                unsigned pos = atomicAdd(cnt, 1u);
                if (pos < CAP) { cand_s[pos] = vv[j]; cand_i[pos] = i * 4 + j; }
            }
        }
    }
}

// ------- Pass 3: sort the ~100 candidates, emit top-k ---------------------------
__global__ __launch_bounds__(256) void k_final(const float* __restrict__ cand_s,
                                               const int* __restrict__ cand_i,
                                               const unsigned* __restrict__ cnt,
                                               int k, float* __restrict__ out) {
    __shared__ float ss[CAP];
    __shared__ int   si[CAP];
    const int tid = threadIdx.x;
    unsigned c = *cnt;
    const int n = (c > CAP) ? CAP : (int)c;
    int N = 64; while (N < n) N <<= 1;   // pow2 >= n (runtime-sized bitonic)
    for (int i = tid; i < N; i += 256) {
        const bool v = i < n;
        ss[i] = v ? cand_s[i] : NEG_INF;
        si[i] = v ? cand_i[i] : 0x7fffffff;
    }
    __syncthreads();
    for (int kk = 2; kk <= N; kk <<= 1) {
        for (int j = kk >> 1; j > 0; j >>= 1) {
            for (int i = tid; i < N; i += 256) {
                int l = i ^ j;
                if (l > i) {
                    float s_i = ss[i], s_l = ss[l];
                    int   d_i = si[i], d_l = si[l];
                    bool sw = ((i & kk) == 0) ? pair_gt(s_l, d_l, s_i, d_i)
                                              : pair_gt(s_i, d_i, s_l, d_l);
                    if (sw) { ss[i] = s_l; si[i] = d_l; ss[l] = s_i; si[l] = d_i; }
                }
            }
            __syncthreads();
        }
    }
    if (tid < k) {
        out[tid]     = ss[tid];
        out[k + tid] = (float)si[tid];   // indices < 2^24: exact in fp32
    }
}

extern "C" void kernel_launch(void* const* d_in, const int* in_sizes, int n_in,
                              void* d_out, int out_size, void* d_ws, size_t ws_size,
                              hipStream_t stream) {
    const float* emb   = (const float*)d_in[0];
    const int*   p_idx = (const int*)d_in[1];
    const int n_items  = in_sizes[0] / 64;   // 1,000,000
    const int k        = out_size / 2;       // 50

    // ws layout (4-byte units)
    float*    scores = (float*)d_ws;
    unsigned* hist   = (unsigned*)(scores + n_items);      // [NBKT]
    unsigned* cnt    = hist + NBKT;                        // candidate counter
    float*    cand_s = (float*)(cnt + 1);
    int*      cand_i = (int*)(cand_s + CAP);

    // zero hist + cnt in one async memset (graph-capture safe)
    hipMemsetAsync(hist, 0, (NBKT + 1) * sizeof(unsigned), stream);

    const int n4 = n_items / 4;
    k_gemv_hist<<<1024, 256, 0, stream>>>(emb, p_idx, n_items, scores, hist);
    k_compact  <<<256,  256, 0, stream>>>(scores, n4, hist, k, cnt, cand_s, cand_i);
    k_final    <<<1,    256, 0, stream>>>(cand_s, cand_i, cnt, k, (float*)d_out);
}